// Round 15
// baseline (142.442 us; speedup 1.0000x reference)
//
#include <hip/hip_runtime.h>

#define N 4096
#define NBINS 10            // bins 0..9 accumulated; bin 10 analytic
#define BLOCK 256
#define NSLOTS 64           // spread-atomic slots, 64 B apart
#define NGRP 8              // 8 groups of 2 float4 per lane (64 elems/lane)
#define GF4 2

// R13 post-mortem: forced packed-fp32 asm (2x fewer issue slots) was NEUTRAL
// -> execute phase is not issue-bound. Untested axis: occupancy. All kernels
// since R9 sit at VGPR 52-88 = 16 waves/CU (m69: waves halve at vgpr>64).
// R14: lean-register redesign targeting <=64 VGPR -> 32 waves/CU:
//   - scalar accumulators (20), clamp-fold arithmetic (R11 lesson)
//   - prefetch depth 2 float4 (16 VGPR), double-buffered
//   - mask built in prologue in 4 chunks of 4 ushort4 (transient 8 VGPR)
//   - main loop batch-only (R9 vmcnt-order fix)
// Guard: if this spills (R3 pathology), WRITE_SIZE explodes -> revert.

// Kernel A: cid recovery (validated R6-R13, absmax=0). cid[i] = column of
// first 1 in row i (ushort, 8 KB). Block 0 zeroes the atomic slots.
__global__ __launch_bounds__(BLOCK) void fastap_cid_kernel(
    const float* __restrict__ labels, unsigned short* __restrict__ cid,
    float* __restrict__ slots)
{
    if (blockIdx.x == 0 && threadIdx.x < NSLOTS)
        slots[threadIdx.x * 16] = 0.f;

    const int lane = threadIdx.x & 63;
    const int wid  = (blockIdx.x * BLOCK + threadIdx.x) >> 6;
    #pragma unroll
    for (int rr = 0; rr < 4; ++rr) {
        const int row = wid * 4 + rr;
        const float4* l4 = (const float4*)(labels + (size_t)row * N);
        bool done = false;
        for (int r = 0; !done; ++r) {                // terminates at diagonal
            float4 v = l4[r * 64 + lane];
            bool any = (v.x > 0.5f) || (v.y > 0.5f) || (v.z > 0.5f) || (v.w > 0.5f);
            unsigned long long m = __ballot(any);
            if (m) {
                int fl = __builtin_ctzll(m);
                if (lane == fl) {
                    int e = (v.x > 0.5f) ? 0 : (v.y > 0.5f) ? 1 : (v.z > 0.5f) ? 2 : 3;
                    cid[row] = (unsigned short)(r * 256 + lane * 4 + e);
                }
                done = true;
            }
        }
    }
}

// Kernel B: one row per wave, no barriers; chunked mask prologue; depth-2
// rolling batch prefetch; scalar clamp-fold bin loop.
__global__ __launch_bounds__(BLOCK, 8) void fastap_row_kernel(
    const float* __restrict__ batch, const unsigned short* __restrict__ cid,
    float* __restrict__ slots)
{
    const int tid  = threadIdx.x;
    const int lane = tid & 63;
    const int row  = (blockIdx.x * BLOCK + tid) >> 6;   // global wave id

    const float4*  b4 = (const float4*)(batch + (size_t)row * N);
    const ushort4* c4 = (const ushort4*)cid;            // 8 KB, cache-hot
    const int myc = (int)cid[row];                      // wave-uniform

    // --- prologue: mask built in 4 chunks (only 4 ushort4 live at a time) ---
    unsigned mlo = 0u, mhi = 0u;
    #pragma unroll
    for (int ch = 0; ch < 4; ++ch) {
        ushort4 cv[4];
        #pragma unroll
        for (int j = 0; j < 4; ++j) cv[j] = c4[(ch * 4 + j) * 64 + lane];
        #pragma unroll
        for (int j = 0; j < 4; ++j) {
            const int jj = ch * 4 + j;
            unsigned bits = ((int)cv[j].x == myc ? 1u : 0u)
                          | ((int)cv[j].y == myc ? 2u : 0u)
                          | ((int)cv[j].z == myc ? 4u : 0u)
                          | ((int)cv[j].w == myc ? 8u : 0u);
            if (jj < 8) mlo |= bits << (jj * 4);
            else        mhi |= bits << ((jj - 8) * 4);
        }
    }

    // --- depth-2 double-buffered batch prefetch (16 VGPRs) ---
    float4 buf[2][GF4];
    #pragma unroll
    for (int i = 0; i < GF4; ++i) {
        buf[0][i] = b4[(0 * GF4 + i) * 64 + lane];
        buf[1][i] = b4[(1 * GF4 + i) * 64 + lane];
    }

    float hcp[NBINS], hca[NBINS];
    #pragma unroll
    for (int l = 0; l < NBINS; ++l) { hcp[l] = 0.f; hca[l] = 0.f; }

    #pragma unroll
    for (int g = 0; g < NGRP; ++g) {
        // compute on buf[g&1] (oldest outstanding loads); buf[(g+1)&1] stays
        // in flight; g+2 issued after use (WAR-safe: VALU reads at issue).
        const unsigned mw = (g < 4) ? mlo : mhi;
        #pragma unroll
        for (int i = 0; i < GF4; ++i) {
            #pragma unroll
            for (int e = 0; e < 4; ++e) {
                float x   = ((const float*)&buf[g & 1][i])[e];
                float lbl = (float)((mw >> (((g & 3) * 8 + i * 4 + e))) & 1u);
                float u = fmaf(5.f, x, -4.f);     // 1 - dist2/Delta
                #pragma unroll
                for (int l = 0; l < NBINS; ++l) {
                    float c = fminf(fmaxf(u + (float)l, 0.f), 1.f); // add+clamp
                    hcp[l] = fmaf(c, lbl, hcp[l]);
                    hca[l] += c;
                }
            }
        }
        if (g + 2 < NGRP) {
            #pragma unroll
            for (int i = 0; i < GF4; ++i)
                buf[g & 1][i] = b4[((g + 2) * GF4 + i) * 64 + lane];
        }
    }

    float np = (float)(__popc(mlo) + __popc(mhi));

    // butterfly-reduce 21 accumulators across this wave's 64 lanes
    #pragma unroll
    for (int off = 1; off < 64; off <<= 1) {
        #pragma unroll
        for (int l = 0; l < NBINS; ++l) {
            hcp[l] += __shfl_xor(hcp[l], off, 64);
            hca[l] += __shfl_xor(hca[l], off, 64);
        }
        np += __shfl_xor(np, off, 64);
    }

    if (lane == 0) {
        float Hp_prev = 0.f, ap = 0.f;
        #pragma unroll
        for (int l = 0; l < NBINS; ++l) {
            float Hp = hcp[l];
            float Ha = hca[l];
            float hp = Hp - Hp_prev;
            if (Ha > 0.f) ap += hp * Hp / Ha;
            Hp_prev = Hp;
        }
        float Np = np;                                 // >= 1 (diagonal)
        ap += (Np - Hp_prev) * Np * (1.f / (float)N);  // analytic bin 10
        atomicAdd(&slots[(row & (NSLOTS - 1)) * 16], ap / Np);
    }
}

// Kernel C: one wave sums the 64 slots. loss = 1 - sum/N (all rows valid).
__global__ void fastap_finalize(const float* __restrict__ slots,
                                float* __restrict__ out)
{
    const int lane = threadIdx.x;
    float v = slots[lane * 16];
    #pragma unroll
    for (int off = 32; off > 0; off >>= 1)
        v += __shfl_down(v, off, 64);
    if (lane == 0) out[0] = 1.f - v * (1.f / (float)N);
}

extern "C" void kernel_launch(void* const* d_in, const int* in_sizes, int n_in,
                              void* d_out, int out_size, void* d_ws, size_t ws_size,
                              hipStream_t stream) {
    const float* batch  = (const float*)d_in[0];
    const float* labels = (const float*)d_in[1];
    unsigned short* cid = (unsigned short*)d_ws;        // 8 KB
    float* slots = (float*)((char*)d_ws + 8192);        // 64 slots, 64 B apart
    fastap_cid_kernel<<<N / (4 * 4), BLOCK, 0, stream>>>(labels, cid, slots);
    fastap_row_kernel<<<N / 4, BLOCK, 0, stream>>>(batch, cid, slots);
    fastap_finalize<<<1, 64, 0, stream>>>(slots, (float*)d_out);
}